// Round 4
// baseline (356.896 us; speedup 1.0000x reference)
//
#include <hip/hip_runtime.h>
#include <math.h>
#include <stdint.h>

#define B 16
#define C 256
#define H 128
#define W 128
#define HW (H * W)      // 16384
#define HW4 (HW / 4)    // 4096 float4 chunks per image plane

typedef float vfloat4 __attribute__((ext_vector_type(4)));

// ---------------------------------------------------------------------------
// PROBE ROUND (intentional, revert after): discriminate CU-side vs memory-side
// bound for the channel reduction, which runs at ~1.75 TB/s (~155 us) and was
// INVARIANT to access-pattern restructures (1KiB/4KiB chunks, nt/cached).
// Trick: every loaded chunk is read a SECOND time through an opaque pointer
// (asm blocks CSE), hitting L1/L2 -> DRAM traffic unchanged, CU-side work
// (load issue + VALU consume) exactly doubled. Both reads feed the
// accumulators (mean scaled by 1/(2C); max idempotent) so nothing is DCE'd
// and the result stays correct.
//   - If memory-side bound: total ~365-385 us (extra VALU hides under waits).
//   - If CU-side bound:     total ~480-520 us and the reduce kernel becomes
//     visible in the top-5 with its own VALUBusy/FETCH/WRITE counters.
// ---------------------------------------------------------------------------
__global__ __launch_bounds__(512) void reduce_mean_max(
    const float* __restrict__ x, float* __restrict__ feat) {
  const int t    = threadIdx.x;
  const int lane = t & 63;
  const int wv   = t >> 6;                 // wave id 0..7 = channel group
  const int sp   = blockIdx.x;             // span id [0, 256)
  const int b    = sp >> 4;                // 16 spans per image
  const int s4b  = (sp & 15) << 8;         // span base, in float4 chunks

  const vfloat4* xp =
      (const vfloat4*)x + (size_t)(b * C + wv * 32) * HW4 + s4b;

  vfloat4 sum[4], mx[4];
#pragma unroll
  for (int i = 0; i < 4; ++i) {
    sum[i] = (vfloat4)(0.f);
    mx[i]  = (vfloat4)(-INFINITY);
  }

#pragma unroll 4
  for (int c = 0; c < 32; ++c) {
    const vfloat4* p = xp + (size_t)c * HW4;   // one 64 KiB channel step

    // opaque copy of p: compiler cannot prove p2 == p, so the second set of
    // loads below is emitted for real (hits L1/L2 -> no extra DRAM traffic)
    uint32_t plo = (uint32_t)(uintptr_t)p;
    uint32_t phi = (uint32_t)((uintptr_t)p >> 32);
    asm("" : "+v"(plo), "+v"(phi));
    const vfloat4* p2 =
        (const vfloat4*)(((uint64_t)phi << 32) | (uint64_t)plo);

#pragma unroll
    for (int i = 0; i < 4; ++i) {              // pass A: streaming read
      vfloat4 v = p[i * 64 + lane];
      sum[i] += v;
      mx[i].x = fmaxf(mx[i].x, v.x);
      mx[i].y = fmaxf(mx[i].y, v.y);
      mx[i].z = fmaxf(mx[i].z, v.z);
      mx[i].w = fmaxf(mx[i].w, v.w);
    }
#pragma unroll
    for (int i = 0; i < 4; ++i) {              // pass B: hot re-read (probe)
      vfloat4 v = p2[i * 64 + lane];
      sum[i] += v;                             // counted twice -> inv = 1/2C
      mx[i].x = fmaxf(mx[i].x, v.x);           // idempotent
      mx[i].y = fmaxf(mx[i].y, v.y);
      mx[i].z = fmaxf(mx[i].z, v.z);
      mx[i].w = fmaxf(mx[i].w, v.w);
    }
  }

  __shared__ vfloat4 s_buf[8][64][4];          // 32 KiB, reused twice

  // ---- pass 1: sums -> mean plane ----
#pragma unroll
  for (int i = 0; i < 4; ++i) s_buf[wv][lane][i] = sum[i];
  __syncthreads();
  if (t < 256) {
    const int i = t >> 6, l = t & 63;          // chunk j = t = i*64 + l
    vfloat4 a = (vfloat4)(0.f);
#pragma unroll
    for (int w2 = 0; w2 < 8; ++w2) a += s_buf[w2][l][i];
    const float inv = 1.0f / (float)(2 * C);   // each element summed twice
    ((vfloat4*)feat)[(size_t)(b * 2) * HW4 + s4b + t] = a * inv;
  }
  __syncthreads();                             // pass-1 reads done

  // ---- pass 2: maxes -> max plane ----
#pragma unroll
  for (int i = 0; i < 4; ++i) s_buf[wv][lane][i] = mx[i];
  __syncthreads();
  if (t < 256) {
    const int i = t >> 6, l = t & 63;
    vfloat4 m = s_buf[0][l][i];
#pragma unroll
    for (int w2 = 1; w2 < 8; ++w2) {
      vfloat4 v = s_buf[w2][l][i];
      m.x = fmaxf(m.x, v.x);
      m.y = fmaxf(m.y, v.y);
      m.z = fmaxf(m.z, v.z);
      m.w = fmaxf(m.w, v.w);
    }
    ((vfloat4*)feat)[(size_t)(b * 2 + 1) * HW4 + s4b + t] = m;
  }
}

// ---------------------------------------------------------------------------
// Kernel 2: 3x3 conv (2 in-ch -> 1 out-ch, zero pad 1) + sigmoid. UNCHANGED.
// ---------------------------------------------------------------------------
__global__ __launch_bounds__(256) void conv3x3_sigmoid(
    const float* __restrict__ feat, const float* __restrict__ wgt,
    float* __restrict__ out) {
  __shared__ float sw[18];
  if (threadIdx.x < 18) sw[threadIdx.x] = wgt[threadIdx.x];
  __syncthreads();

  const int idx = blockIdx.x * 256 + threadIdx.x;  // [0, 262144)
  const int b = idx >> 14;
  const int s = idx & (HW - 1);
  const int h = s >> 7;
  const int w = s & (W - 1);

  float acc = 0.f;
#pragma unroll
  for (int ci = 0; ci < 2; ++ci) {
    const float* f  = feat + (size_t)(b * 2 + ci) * HW;
    const float* kw = sw + ci * 9;
#pragma unroll
    for (int dh = -1; dh <= 1; ++dh) {
      const int hh = h + dh;
      if (hh < 0 || hh >= H) continue;
      const float* row = f + hh * W;
#pragma unroll
      for (int dw = -1; dw <= 1; ++dw) {
        const int ww = w + dw;
        if (ww < 0 || ww >= W) continue;
        acc += row[ww] * kw[(dh + 1) * 3 + (dw + 1)];
      }
    }
  }
  out[idx] = 1.f / (1.f + __expf(-acc));
}

extern "C" void kernel_launch(void* const* d_in, const int* in_sizes, int n_in,
                              void* d_out, int out_size, void* d_ws, size_t ws_size,
                              hipStream_t stream) {
  const float* x   = (const float*)d_in[0];   // [16, 256, 128, 128] fp32
  const float* wgt = (const float*)d_in[1];   // [1, 2, 3, 3] fp32
  float* out  = (float*)d_out;                // [16, 1, 128, 128] fp32
  float* feat = (float*)d_ws;                 // [16, 2, 128, 128] fp32 = 2 MB scratch

  // 256 spans (16 images x 16 spans of 4 KiB), 512 threads each
  reduce_mean_max<<<256, 512, 0, stream>>>(x, feat);
  // 262144 outputs / 256 threads = 1024 blocks
  conv3x3_sigmoid<<<1024, 256, 0, stream>>>(feat, wgt, out);
}